// Round 1
// baseline (292.584 us; speedup 1.0000x reference)
//
#include <hip/hip_runtime.h>
#include <math.h>

// Problem constants (from reference setup_inputs)
#define BB 128      // batch
#define NN 2000     // nodes
#define EE 20000    // edges
#define CC 16       // channels
#define N_IN 200
#define FUNC_LO 200   // func nodes: [200, 1800)
#define FUNC_HI 1800
#define OUT_LO 1800   // output nodes: [1800, 2000)
#define LAYERS 4
#define EPSV 1e-5f

// ---------------- CSR build ----------------

__global__ void k_hist(const int* __restrict__ dst, int* __restrict__ deg) {
    int e = blockIdx.x * 256 + threadIdx.x;
    if (e < EE) atomicAdd(&deg[dst[e]], 1);
}

// exclusive scan of deg[0..NN) -> rs[0..NN], also copy to cursor
__global__ void k_scan(const int* __restrict__ deg, int* __restrict__ rs,
                       int* __restrict__ cursor) {
    const int PER = 8; // 256*8 = 2048 >= NN
    int tid = threadIdx.x;
    int vals[PER];
    int s = 0;
    #pragma unroll
    for (int i = 0; i < PER; i++) {
        int idx = tid * PER + i;
        int d = (idx < NN) ? deg[idx] : 0;
        vals[i] = s;     // prefix within this thread's chunk (exclusive)
        s += d;
    }
    __shared__ int ts[256];
    ts[tid] = s;
    __syncthreads();
    // Hillis-Steele inclusive scan over thread totals
    for (int off = 1; off < 256; off <<= 1) {
        int v = 0;
        if (tid >= off) v = ts[tid - off];
        __syncthreads();
        ts[tid] += v;
        __syncthreads();
    }
    int base = (tid == 0) ? 0 : ts[tid - 1];
    #pragma unroll
    for (int i = 0; i < PER; i++) {
        int idx = tid * PER + i;
        if (idx < NN) {
            int v = base + vals[i];
            rs[idx] = v;
            cursor[idx] = v;
        }
    }
    if (tid == 255) rs[NN] = ts[255];
}

__global__ void k_scatter(const int* __restrict__ dst, int* __restrict__ cursor,
                          int* __restrict__ csr) {
    int e = blockIdx.x * 256 + threadIdx.x;
    if (e < EE) {
        int p = atomicAdd(&cursor[dst[e]], 1);
        csr[p] = e;
    }
}

// ---------------- data movement ----------------

// xT[n*B + b] = x[b*N + n]
__global__ void k_transpose(const float* __restrict__ x, float* __restrict__ xT) {
    int idx = blockIdx.x * 256 + threadIdx.x; // coalesced read over x
    if (idx < BB * NN) {
        int b = idx / NN;
        int n = idx - b * NN;
        xT[n * BB + b] = x[idx];
    }
}

// x0[e*B + b] = xT[src[e]*B + b]
__global__ void k_gather(const float* __restrict__ xT, const int* __restrict__ src,
                         float* __restrict__ x0) {
    int t = blockIdx.x * 256 + threadIdx.x;
    int e = t >> 7;
    int b = t & 127;
    if (e < EE) x0[t] = xT[src[e] * BB + b];
}

// ---------------- per-node fused layer kernel ----------------
// One workgroup per node n (256 threads). Thread = (brow = tid>>4, c = tid&15);
// each thread owns b = brow + 16*j, j=0..7 for channel c.
// Computes: h = segsum_e(xe[b,e]*w1[e,c]) -> bn1 -> elu -> h2 = h @ w2m[n] ->
// bn2 -> elu -> hbuf[n,b,c].  (b1,b2 cancel exactly through batchnorm.)
__global__ __launch_bounds__(256) void k_node(
    const float* __restrict__ xe,   // (E, B)
    const float* __restrict__ w1,   // (E, C)
    const float* __restrict__ w2,   // (N, C, C)
    const float* __restrict__ g1, const float* __restrict__ be1,
    const float* __restrict__ g2, const float* __restrict__ be2,
    const int* __restrict__ rs, const int* __restrict__ csr,
    float* __restrict__ hbuf)       // (N, B, C)
{
    int n = blockIdx.x;
    int tid = threadIdx.x;
    int c = tid & 15;
    int brow = tid >> 4;

    __shared__ float lds_w2[256];
    __shared__ float lds_a[BB * CC];     // 8 KB
    __shared__ float red_s[256], red_ss[256];
    __shared__ float sc[16], sh[16];

    float fm = (n >= FUNC_LO && n < FUNC_HI) ? 1.0f : 0.0f;
    lds_w2[tid] = w2[n * 256 + tid] * fm;

    int start = rs[n], end = rs[n + 1];

    float acc[8];
    #pragma unroll
    for (int j = 0; j < 8; j++) acc[j] = 0.0f;

    for (int k = start; k < end; k++) {
        int e = csr[k];
        float w = w1[e * CC + c];
        const float* xr = xe + (size_t)e * BB + brow;
        #pragma unroll
        for (int j = 0; j < 8; j++) acc[j] += xr[16 * j] * w;
    }

    // ---- bn1 stats (per (n,c), over 128 b) ----
    float s = 0.f, ss = 0.f;
    #pragma unroll
    for (int j = 0; j < 8; j++) { s += acc[j]; ss += acc[j] * acc[j]; }
    red_s[tid] = s; red_ss[tid] = ss;
    __syncthreads();
    if (tid < 16) {
        float S = 0.f, SS = 0.f;
        #pragma unroll
        for (int r = 0; r < 16; r++) { S += red_s[r * 16 + tid]; SS += red_ss[r * 16 + tid]; }
        float mean = S * (1.0f / 128.0f);
        float var = SS * (1.0f / 128.0f) - mean * mean;
        float scale = rsqrtf(var + EPSV) * g1[n * CC + tid];
        sc[tid] = scale;
        sh[tid] = be1[n * CC + tid] - mean * scale;
    }
    __syncthreads();

    // apply bn1 + elu, write transposed activation tile to LDS
    #pragma unroll
    for (int j = 0; j < 8; j++) {
        float a = acc[j] * sc[c] + sh[c];
        a = (a > 0.0f) ? a : (expf(a) - 1.0f);
        lds_a[(brow + 16 * j) * CC + c] = a;
    }
    __syncthreads();

    // ---- 16x16 node matmul: h2[b,d] = sum_c a[b,c] * w2m[n,c,d], d = this thread's c ----
    float wcol[16];
    #pragma unroll
    for (int q = 0; q < 16; q++) wcol[q] = lds_w2[q * 16 + c];
    float h2[8];
    #pragma unroll
    for (int j = 0; j < 8; j++) {
        const float* ar = &lds_a[(brow + 16 * j) * CC];
        float a2 = 0.f;
        #pragma unroll
        for (int q = 0; q < 16; q++) a2 += ar[q] * wcol[q];
        h2[j] = a2;
    }
    __syncthreads();

    // ---- bn2 stats ----
    s = 0.f; ss = 0.f;
    #pragma unroll
    for (int j = 0; j < 8; j++) { s += h2[j]; ss += h2[j] * h2[j]; }
    red_s[tid] = s; red_ss[tid] = ss;
    __syncthreads();
    if (tid < 16) {
        float S = 0.f, SS = 0.f;
        #pragma unroll
        for (int r = 0; r < 16; r++) { S += red_s[r * 16 + tid]; SS += red_ss[r * 16 + tid]; }
        float mean = S * (1.0f / 128.0f);
        float var = SS * (1.0f / 128.0f) - mean * mean;
        float scale = rsqrtf(var + EPSV) * g2[n * CC + tid];
        sc[tid] = scale;
        sh[tid] = be2[n * CC + tid] - mean * scale;
    }
    __syncthreads();

    #pragma unroll
    for (int j = 0; j < 8; j++) {
        float a = h2[j] * sc[c] + sh[c];
        a = (a > 0.0f) ? a : (expf(a) - 1.0f);
        hbuf[(size_t)n * (BB * CC) + (brow + 16 * j) * CC + c] = a;
    }
}

// ---------------- edge update kernel ----------------
// xe[e,b] = fm(src[e]) * dot_c(hbuf[src[e],b,:], w3[e,:]) + b3[e] + x0[e,b]
__global__ __launch_bounds__(256) void k_edge(
    const float* __restrict__ hbuf, const float* __restrict__ w3,
    const float* __restrict__ b3, const int* __restrict__ src,
    const float* __restrict__ x0, float* __restrict__ xe)
{
    int t = blockIdx.x * 256 + threadIdx.x;
    int e = t >> 7;
    int b = t & 127;
    int sN = src[e];
    float fm = (sN >= FUNC_LO && sN < FUNC_HI) ? 1.0f : 0.0f;
    const float4* hr = (const float4*)(hbuf + (size_t)sN * (BB * CC) + b * CC);
    const float4* wr = (const float4*)(w3 + (size_t)e * CC);
    float a = 0.f;
    #pragma unroll
    for (int i = 0; i < 4; i++) {
        float4 h4 = hr[i];
        float4 w4 = wr[i];
        a += h4.x * w4.x + h4.y * w4.y + h4.z * w4.z + h4.w * w4.w;
    }
    xe[t] = a * fm + b3[e] + x0[t];
}

// ---------------- final masked segment sum ----------------
// out[b*N + n] = sum_{e: dst[e]==n} xe[e,b]   for n in [1800,2000)
__global__ void k_out(const float* __restrict__ xe, const int* __restrict__ rs,
                      const int* __restrict__ csr, float* __restrict__ out)
{
    int n = OUT_LO + blockIdx.x;
    int b = threadIdx.x; // 128 threads
    int st = rs[n], en = rs[n + 1];
    float s = 0.f;
    for (int k = st; k < en; k++) {
        int e = csr[k];
        s += xe[(size_t)e * BB + b];
    }
    out[(size_t)b * NN + n] = s;
}

extern "C" void kernel_launch(void* const* d_in, const int* in_sizes, int n_in,
                              void* d_out, int out_size, void* d_ws, size_t ws_size,
                              hipStream_t stream) {
    const float* x   = (const float*)d_in[0];
    const float* w1  = (const float*)d_in[1];
    // d_in[2] = b1: cancels through batchnorm -> unused
    const float* w2  = (const float*)d_in[3];
    // d_in[4] = b2: cancels through batchnorm -> unused
    const float* w3  = (const float*)d_in[5];
    const float* b3  = (const float*)d_in[6];
    const float* g1  = (const float*)d_in[7];
    const float* be1 = (const float*)d_in[8];
    const float* g2  = (const float*)d_in[9];
    const float* be2 = (const float*)d_in[10];
    const int* ei    = (const int*)d_in[11];
    const int* srcp = ei;
    const int* dstp = ei + EE;
    float* out = (float*)d_out;

    // workspace partition (all offsets 16B-aligned)
    char* ws = (char*)d_ws;
    float* xT   = (float*)ws;                 ws += (size_t)NN * BB * 4;      // 1.0 MB
    float* x0   = (float*)ws;                 ws += (size_t)EE * BB * 4;      // 10.2 MB
    float* xe   = (float*)ws;                 ws += (size_t)EE * BB * 4;      // 10.2 MB
    float* hbuf = (float*)ws;                 ws += (size_t)NN * BB * CC * 4; // 16.4 MB
    int* deg    = (int*)ws;                   ws += (size_t)NN * 4;
    int* rs     = (int*)ws;                   ws += (size_t)(NN + 1) * 4 + 12;
    int* cursor = (int*)ws;                   ws += (size_t)NN * 4;
    int* csr    = (int*)ws;                   ws += (size_t)EE * 4;

    // CSR build (same work every call; graph-capture safe)
    hipMemsetAsync(deg, 0, NN * sizeof(int), stream);
    k_hist<<<(EE + 255) / 256, 256, 0, stream>>>(dstp, deg);
    k_scan<<<1, 256, 0, stream>>>(deg, rs, cursor);
    k_scatter<<<(EE + 255) / 256, 256, 0, stream>>>(dstp, cursor, csr);

    // x0 = x[:, src] in (E,B) layout
    k_transpose<<<(NN * BB + 255) / 256, 256, 0, stream>>>(x, xT);
    k_gather<<<(EE * BB) / 256, 256, 0, stream>>>(xT, srcp, x0);

    const float* cur = x0;
    for (int l = 0; l < LAYERS; l++) {
        k_node<<<NN, 256, 0, stream>>>(cur, w1, w2, g1, be1, g2, be2, rs, csr, hbuf);
        k_edge<<<(EE * BB) / 256, 256, 0, stream>>>(hbuf, w3, b3, srcp, x0, xe);
        cur = xe;
    }

    hipMemsetAsync(d_out, 0, (size_t)out_size * sizeof(float), stream);
    k_out<<<NN - OUT_LO, BB, 0, stream>>>(xe, rs, csr, out);
}

// Round 2
// 203.363 us; speedup vs baseline: 1.4387x; 1.4387x over previous
//
#include <hip/hip_runtime.h>
#include <math.h>

// Problem constants (from reference setup_inputs)
#define BB 128      // batch
#define NN 2000     // nodes
#define EE 20000    // edges
#define CC 16       // channels
#define FUNC_LO 200   // func nodes: [200, 1800)
#define FUNC_HI 1800
#define OUT_LO 1800   // output nodes: [1800, 2000)
#define LAYERS 4
#define EPSV 1e-5f
#define CH 32         // edge chunk size (deg avg ~10, Poisson tail << 32; chunk loop handles any)
#define HP 129        // padded LDS stride (128+1) — conflict-free b-contiguous access

// ---------------- CSR build: concatenated [dst-degrees | src-degrees] ----------------

__global__ void k_hist2(const int* __restrict__ ei, int* __restrict__ deg) {
    int e = blockIdx.x * 256 + threadIdx.x;
    if (e < EE) {
        atomicAdd(&deg[ei[EE + e]], 1);      // dst (incoming)
        atomicAdd(&deg[NN + ei[e]], 1);      // src (outgoing)
    }
}

// exclusive scan of deg[0..2N) -> rs[0..2N], copy to cursor
__global__ void k_scan(const int* __restrict__ deg, int* __restrict__ rs,
                       int* __restrict__ cursor) {
    const int PER = 16; // 256*16 = 4096 >= 2*NN
    int tid = threadIdx.x;
    int vals[PER];
    int s = 0;
    #pragma unroll
    for (int i = 0; i < PER; i++) {
        int idx = tid * PER + i;
        int d = (idx < 2 * NN) ? deg[idx] : 0;
        vals[i] = s;
        s += d;
    }
    __shared__ int ts[256];
    ts[tid] = s;
    __syncthreads();
    for (int off = 1; off < 256; off <<= 1) {
        int v = (tid >= off) ? ts[tid - off] : 0;
        __syncthreads();
        ts[tid] += v;
        __syncthreads();
    }
    int base = (tid == 0) ? 0 : ts[tid - 1];
    #pragma unroll
    for (int i = 0; i < PER; i++) {
        int idx = tid * PER + i;
        if (idx < 2 * NN) {
            int v = base + vals[i];
            rs[idx] = v;
            cursor[idx] = v;
        }
    }
    if (tid == 255) rs[2 * NN] = ts[255];
}

__global__ void k_scatter2(const int* __restrict__ ei, int* __restrict__ cursor,
                           int* __restrict__ csr) {
    int e = blockIdx.x * 256 + threadIdx.x;
    if (e < EE) {
        int p = atomicAdd(&cursor[ei[EE + e]], 1);   // dst-CSR in csr[0..E)
        csr[p] = e;
        int q = atomicAdd(&cursor[NN + ei[e]], 1);   // src-CSR in csr[E..2E)
        csr[q] = e;
    }
}

// xT[n*B + b] = x[b*N + n]
__global__ void k_transpose(const float* __restrict__ x, float* __restrict__ xT) {
    int idx = blockIdx.x * 256 + threadIdx.x;
    if (idx < BB * NN) {
        int b = idx / NN;
        int n = idx - b * NN;
        xT[n * BB + b] = x[idx];
    }
}

// ---------------- fused push-based layer kernel ----------------
// One block per node n. 256 threads = (half = tid>>7, b = tid&127).
// Phase A: gather incoming edges (dst-CSR), h[c][b] = sum_e xe_in[row(e)+b]*w1[e,c]
// Phase B: bn1 -> elu -> 16x16 matmul w2 -> bn2 -> elu  (all in LDS; b1,b2 cancel in bn)
// Phase C: for each outgoing edge (src-CSR): xe_out[e,b] = dot_c(a[c][b],w3[e,c]) + b3[e] + xT[n,b]
// Non-func nodes (w2m=w3m=0): skip A/B, phase C writes b3[e] + xT[n,b].
__global__ __launch_bounds__(256) void k_layer(
    const float* __restrict__ xe_in,   // (E,B) rows, or xT when srcmap != null (layer 0)
    const int* __restrict__ srcmap,    // layer 0: src ids (row = srcmap[e]*BB); else null
    const float* __restrict__ xT,      // (N,B) residual rows
    const float* __restrict__ w1, const float* __restrict__ w2,
    const float* __restrict__ w3, const float* __restrict__ b3,
    const float* __restrict__ g1, const float* __restrict__ be1,
    const float* __restrict__ g2, const float* __restrict__ be2,
    const int* __restrict__ rs, const int* __restrict__ csr,
    const int* __restrict__ dstmap,    // last layer: dst ids for write masking; else null
    float* __restrict__ xe_out)        // (E,B)
{
    int n = blockIdx.x;
    int tid = threadIdx.x;
    int b = tid & 127;
    int half = tid >> 7;

    __shared__ float lds_h[CC * HP];     // 8.25 KB: h tile, then activated a2 tile [d][b]
    __shared__ float lds_w2[256];
    __shared__ float lds_w[CH * CC];     // chunk of w1 or w3 rows
    __shared__ int   lds_e[CH];
    __shared__ int   lds_roff[CH];
    __shared__ float lds_bias[CH];
    __shared__ int   lds_wr[CH];
    __shared__ float red_s[256], red_ss[256];
    __shared__ float sc[CC], sh[CC];

    const bool isfunc = (n >= FUNC_LO && n < FUNC_HI);   // block-uniform
    float x0r = xT[n * BB + b];

    if (isfunc) {
        lds_w2[tid] = w2[n * 256 + tid];

        // ---- Phase A: weighted segment-sum over incoming edges ----
        float acc[CC];
        #pragma unroll
        for (int c = 0; c < CC; c++) acc[c] = 0.0f;

        int st = rs[n], en = rs[n + 1];
        for (int k0 = st; k0 < en; k0 += CH) {
            int m = min(CH, en - k0);
            if (tid < m) {
                int e = csr[k0 + tid];
                lds_e[tid] = e;
                lds_roff[tid] = (srcmap ? srcmap[e] : e) * BB;
            }
            __syncthreads();
            for (int idx = tid; idx < m * CC; idx += 256)
                lds_w[idx] = w1[(size_t)lds_e[idx >> 4] * CC + (idx & 15)];
            __syncthreads();
            for (int k = half; k < m; k += 2) {
                float v = xe_in[lds_roff[k] + b];      // coalesced 256B per wave
                const float* wr = &lds_w[k * CC];
                #pragma unroll
                for (int c = 0; c < CC; c++) acc[c] += v * wr[c];
            }
            __syncthreads();
        }

        // combine halves into lds_h[c][b]
        if (half) {
            #pragma unroll
            for (int c = 0; c < CC; c++) lds_h[c * HP + b] = acc[c];
        }
        __syncthreads();
        if (!half) {
            #pragma unroll
            for (int c = 0; c < CC; c++) lds_h[c * HP + b] += acc[c];
        }
        __syncthreads();

        // ---- bn1 stats (per c, over 128 b) ----
        {
            int c = tid & 15, r = tid >> 4;
            float s = 0.f, ss = 0.f;
            #pragma unroll
            for (int i = 0; i < 8; i++) {
                float v = lds_h[c * HP + r * 8 + i];
                s += v; ss += v * v;
            }
            red_s[tid] = s; red_ss[tid] = ss;
        }
        __syncthreads();
        if (tid < CC) {
            float S = 0.f, SS = 0.f;
            #pragma unroll
            for (int r = 0; r < 16; r++) { S += red_s[r * 16 + tid]; SS += red_ss[r * 16 + tid]; }
            float mean = S * (1.0f / 128.0f);
            float var = SS * (1.0f / 128.0f) - mean * mean;
            float scale = rsqrtf(var + EPSV) * g1[n * CC + tid];
            sc[tid] = scale;
            sh[tid] = be1[n * CC + tid] - mean * scale;
        }
        __syncthreads();

        // apply bn1 + elu in place
        for (int idx = tid; idx < CC * BB; idx += 256) {
            int c = idx >> 7, b2 = idx & 127;
            float a = lds_h[c * HP + b2] * sc[c] + sh[c];
            a = (a > 0.0f) ? a : (__expf(a) - 1.0f);
            lds_h[c * HP + b2] = a;
        }
        __syncthreads();

        // ---- 16x16 matmul: thread (d = tid&15, brow = tid>>4) ----
        int d = tid & 15, brow = tid >> 4;
        float h2[8];
        #pragma unroll
        for (int j = 0; j < 8; j++) {
            float a2 = 0.f;
            #pragma unroll
            for (int c = 0; c < CC; c++)
                a2 += lds_h[c * HP + brow + 16 * j] * lds_w2[c * 16 + d];
            h2[j] = a2;
        }

        // ---- bn2 stats ----
        float s = 0.f, ss = 0.f;
        #pragma unroll
        for (int j = 0; j < 8; j++) { s += h2[j]; ss += h2[j] * h2[j]; }
        red_s[tid] = s; red_ss[tid] = ss;
        __syncthreads();
        if (tid < CC) {
            float S = 0.f, SS = 0.f;
            #pragma unroll
            for (int r = 0; r < 16; r++) { S += red_s[r * 16 + tid]; SS += red_ss[r * 16 + tid]; }
            float mean = S * (1.0f / 128.0f);
            float var = SS * (1.0f / 128.0f) - mean * mean;
            float scale = rsqrtf(var + EPSV) * g2[n * CC + tid];
            sc[tid] = scale;
            sh[tid] = be2[n * CC + tid] - mean * scale;
        }
        __syncthreads();

        // apply bn2 + elu, store activated tile as [d][b] (all matmul reads done)
        #pragma unroll
        for (int j = 0; j < 8; j++) {
            float a = h2[j] * sc[d] + sh[d];
            a = (a > 0.0f) ? a : (__expf(a) - 1.0f);
            lds_h[d * HP + brow + 16 * j] = a;
        }
        __syncthreads();
    }

    // ---- Phase C: push to outgoing edges ----
    int st2 = rs[NN + n], en2 = rs[NN + n + 1];
    const bool last = (dstmap != nullptr);
    for (int k0 = st2; k0 < en2; k0 += CH) {
        int m = min(CH, en2 - k0);
        if (tid < m) {
            int e = csr[EE + 0 + k0 + tid - EE];   // src-CSR entries live at csr[k0..] directly
            e = csr[k0 + tid];
            lds_e[tid] = e;
            lds_bias[tid] = b3[e];
            lds_wr[tid] = last ? (dstmap[e] >= OUT_LO ? 1 : 0) : 1;
        }
        __syncthreads();
        if (isfunc) {
            for (int idx = tid; idx < m * CC; idx += 256)
                lds_w[idx] = w3[(size_t)lds_e[idx >> 4] * CC + (idx & 15)];
        }
        __syncthreads();
        for (int k = half; k < m; k += 2) {
            if (!lds_wr[k]) continue;
            float dot = 0.f;
            if (isfunc) {
                const float* wr = &lds_w[k * CC];
                #pragma unroll
                for (int d2 = 0; d2 < CC; d2++) dot += lds_h[d2 * HP + b] * wr[d2];
            }
            xe_out[(size_t)lds_e[k] * BB + b] = dot + lds_bias[k] + x0r;
        }
        __syncthreads();
    }
}

// ---------------- final masked segment sum ----------------
__global__ void k_out(const float* __restrict__ xe, const int* __restrict__ rs,
                      const int* __restrict__ csr, float* __restrict__ out)
{
    int n = OUT_LO + blockIdx.x;
    int b = threadIdx.x; // 128 threads
    int st = rs[n], en = rs[n + 1];
    float s = 0.f;
    for (int k = st; k < en; k++) {
        int e = csr[k];
        s += xe[(size_t)e * BB + b];
    }
    out[(size_t)b * NN + n] = s;
}

extern "C" void kernel_launch(void* const* d_in, const int* in_sizes, int n_in,
                              void* d_out, int out_size, void* d_ws, size_t ws_size,
                              hipStream_t stream) {
    const float* x   = (const float*)d_in[0];
    const float* w1  = (const float*)d_in[1];
    // d_in[2] = b1: cancels through batchnorm
    const float* w2  = (const float*)d_in[3];
    // d_in[4] = b2: cancels through batchnorm
    const float* w3  = (const float*)d_in[5];
    const float* b3  = (const float*)d_in[6];
    const float* g1  = (const float*)d_in[7];
    const float* be1 = (const float*)d_in[8];
    const float* g2  = (const float*)d_in[9];
    const float* be2 = (const float*)d_in[10];
    const int* ei    = (const int*)d_in[11];
    const int* srcp  = ei;
    const int* dstp  = ei + EE;
    float* out = (float*)d_out;

    // workspace partition
    char* ws = (char*)d_ws;
    float* xT  = (float*)ws;  ws += (size_t)NN * BB * 4;   // 1.0 MB
    float* xeA = (float*)ws;  ws += (size_t)EE * BB * 4;   // 10.2 MB
    float* xeB = (float*)ws;  ws += (size_t)EE * BB * 4;   // 10.2 MB
    int* deg    = (int*)ws;   ws += (size_t)2 * NN * 4;
    int* rs     = (int*)ws;   ws += (size_t)(2 * NN + 1) * 4 + 12;
    int* cursor = (int*)ws;   ws += (size_t)2 * NN * 4;
    int* csr    = (int*)ws;   ws += (size_t)2 * EE * 4;    // [dst-CSR | src-CSR]

    hipMemsetAsync(deg, 0, 2 * NN * sizeof(int), stream);
    k_hist2<<<(EE + 255) / 256, 256, 0, stream>>>(ei, deg);
    k_scan<<<1, 256, 0, stream>>>(deg, rs, cursor);
    k_scatter2<<<(EE + 255) / 256, 256, 0, stream>>>(ei, cursor, csr);
    k_transpose<<<(NN * BB + 255) / 256, 256, 0, stream>>>(x, xT);

    k_layer<<<NN, 256, 0, stream>>>(xT,  srcp,    xT, w1, w2, w3, b3, g1, be1, g2, be2, rs, csr, nullptr, xeA);
    k_layer<<<NN, 256, 0, stream>>>(xeA, nullptr, xT, w1, w2, w3, b3, g1, be1, g2, be2, rs, csr, nullptr, xeB);
    k_layer<<<NN, 256, 0, stream>>>(xeB, nullptr, xT, w1, w2, w3, b3, g1, be1, g2, be2, rs, csr, nullptr, xeA);
    k_layer<<<NN, 256, 0, stream>>>(xeA, nullptr, xT, w1, w2, w3, b3, g1, be1, g2, be2, rs, csr, dstp,    xeB);

    hipMemsetAsync(d_out, 0, (size_t)out_size * sizeof(float), stream);
    k_out<<<NN - OUT_LO, BB, 0, stream>>>(xeB, rs, csr, out);
}

// Round 3
// 195.660 us; speedup vs baseline: 1.4954x; 1.0394x over previous
//
#include <hip/hip_runtime.h>
#include <math.h>

// Problem constants (from reference setup_inputs)
#define BB 128        // batch
#define NN 2000       // nodes
#define EE 20000      // edges
#define CC 16         // channels
#define FUNC_LO 200   // func nodes: [200, 1800)
#define FUNC_HI 1800
#define OUT_LO 1800   // output nodes: [1800, 2000)
#define OUTN 200
#define EPSV 1e-5f
#define CH 64         // edge chunk (Poisson(10) max-deg << 64; chunk loop handles any)
#define HP 129        // padded LDS stride (128+1)

// ---------------- prep 1: histogram degrees + transpose x + zero outT ----------------
// grid covers BB*NN = 256000 threads (>= EE and >= OUTN*BB). deg must be pre-zeroed.
__global__ void k_prep1(const float* __restrict__ x, float* __restrict__ xT,
                        const int* __restrict__ ei, int* __restrict__ deg,
                        float* __restrict__ outT) {
    int idx = blockIdx.x * 256 + threadIdx.x;
    if (idx < EE) {
        atomicAdd(&deg[ei[EE + idx]], 1);        // in-degree (dst)
        atomicAdd(&deg[NN + ei[idx]], 1);        // out-degree (src)
    }
    if (idx < OUTN * BB) outT[idx] = 0.0f;
    // transpose: x is (B,N) read coalesced
    int b = idx / NN;
    int n = idx - b * NN;
    if (idx < BB * NN) xT[n * BB + b] = x[idx];
}

// exclusive scan of deg[0..2N) -> rs[0..2N], copy to cursor
__global__ void k_scan(const int* __restrict__ deg, int* __restrict__ rs,
                       int* __restrict__ cursor) {
    const int PER = 16; // 256*16 = 4096 >= 2*NN
    int tid = threadIdx.x;
    int vals[PER];
    int s = 0;
    #pragma unroll
    for (int i = 0; i < PER; i++) {
        int idx = tid * PER + i;
        int d = (idx < 2 * NN) ? deg[idx] : 0;
        vals[i] = s;
        s += d;
    }
    __shared__ int ts[256];
    ts[tid] = s;
    __syncthreads();
    for (int off = 1; off < 256; off <<= 1) {
        int v = (tid >= off) ? ts[tid - off] : 0;
        __syncthreads();
        ts[tid] += v;
        __syncthreads();
    }
    int base = (tid == 0) ? 0 : ts[tid - 1];
    #pragma unroll
    for (int i = 0; i < PER; i++) {
        int idx = tid * PER + i;
        if (idx < 2 * NN) {
            int v = base + vals[i];
            rs[idx] = v;
            cursor[idx] = v;
        }
    }
    if (tid == 255) rs[2 * NN] = ts[255];
}

// scatter edges into dst-CSR (csr[0..E)) and src-CSR (csr[E..2E)); record pos[e] in dst-CSR
__global__ void k_scatter2(const int* __restrict__ ei, int* __restrict__ cursor,
                           int* __restrict__ csr, int* __restrict__ pos) {
    int e = blockIdx.x * 256 + threadIdx.x;
    if (e < EE) {
        int p = atomicAdd(&cursor[ei[EE + e]], 1);
        csr[p] = e;
        pos[e] = p;
        int q = atomicAdd(&cursor[NN + ei[e]], 1);
        csr[q] = e;
    }
}

// pre-gather per-edge operands into CSR order (removes all indirection from the layers)
// grid = EE*CC/256 threads
__global__ void k_presort(const int* __restrict__ ei, const int* __restrict__ csr,
                          const int* __restrict__ pos,
                          const float* __restrict__ w1, const float* __restrict__ w3,
                          const float* __restrict__ b3,
                          float* __restrict__ w1s, float* __restrict__ w3s,
                          float* __restrict__ b3s, int* __restrict__ row0s,
                          int* __restrict__ wout, int* __restrict__ dsts) {
    int t = blockIdx.x * 256 + threadIdx.x;
    if (t < EE * CC) {
        int k = t >> 4, c = t & 15;
        w1s[t] = w1[(size_t)csr[k] * CC + c];          // dst-CSR order
        w3s[t] = w3[(size_t)csr[EE + k] * CC + c];     // src-CSR order
    }
    if (t < EE) {
        int e1 = csr[t];
        row0s[t] = ei[e1] * BB;                        // src node row (layer-0 input)
        int e2 = csr[EE + t];
        b3s[t]  = b3[e2];
        wout[t] = pos[e2] * BB;                        // write target = dst-CSR slot
        dsts[t] = ei[EE + e2];                         // dst node (last-layer mask/atomic)
    }
}

// ---------------- fused push-based layer kernel (streaming, permuted edge layout) ----
// One block per node n. 256 threads = (half = tid>>7, b = tid&127).
// Phase A: h[c][b] = sum_{k in [rs[n],rs[n+1])} xe_in[row(k)+b] * w1s[k,c]  (contiguous!)
// Phase B: bn1 -> elu -> 16x16 matmul w2 -> bn2 -> elu  (b1,b2 cancel in bn)
// Phase C: per outgoing entry j: val = dot_d(a[d][b],w3s[j,d]) + b3s[j] + xT[n,b];
//          normal layers: xe_out[wout[j]+b] = val; last layer: atomicAdd outT if dst>=1800.
__global__ __launch_bounds__(256) void k_layer(
    const float* __restrict__ xe_in,   // permuted (E,B); layer 0: xT with row0s
    const int* __restrict__ row0s,     // non-null only for layer 0
    const float* __restrict__ xT,
    const float* __restrict__ w1s, const float* __restrict__ w2,
    const float* __restrict__ w3s, const float* __restrict__ b3s,
    const int* __restrict__ wout,
    const float* __restrict__ g1, const float* __restrict__ be1,
    const float* __restrict__ g2, const float* __restrict__ be2,
    const int* __restrict__ rs,
    const int* __restrict__ dsts,      // non-null only for last layer
    float* __restrict__ xe_out,
    float* __restrict__ outT)
{
    int n = blockIdx.x;
    int tid = threadIdx.x;
    int b = tid & 127;
    int half = tid >> 7;

    __shared__ float lds_h[CC * HP];     // 8.25 KB
    __shared__ float lds_w2[256];
    __shared__ float lds_w[CH * CC];     // 4 KB chunk of w1s/w3s rows
    __shared__ int   lds_i[CH];
    __shared__ float lds_b[CH];
    __shared__ float red_s[256], red_ss[256];
    __shared__ float sc[CC], sh[CC];

    const bool isfunc = (n >= FUNC_LO && n < FUNC_HI);   // block-uniform
    float x0r = xT[n * BB + b];

    if (isfunc) {
        lds_w2[tid] = w2[n * 256 + tid];

        // ---- Phase A: streaming weighted segment-sum over incoming slots ----
        float acc[CC];
        #pragma unroll
        for (int c = 0; c < CC; c++) acc[c] = 0.0f;

        int st = rs[n], en = rs[n + 1];
        for (int k0 = st; k0 < en; k0 += CH) {
            int m = min(CH, en - k0);
            for (int idx = tid; idx < m * CC; idx += 256)
                lds_w[idx] = w1s[(size_t)k0 * CC + idx];           // contiguous
            if (row0s && tid < m) lds_i[tid] = row0s[k0 + tid];
            __syncthreads();
            for (int k = half; k < m; k += 2) {
                int off = row0s ? lds_i[k] : (k0 + k) * BB;
                float v = xe_in[off + b];                          // contiguous rows
                const float* wr = &lds_w[k * CC];
                #pragma unroll
                for (int c = 0; c < CC; c++) acc[c] += v * wr[c];
            }
            __syncthreads();
        }

        // combine halves into lds_h[c][b]
        if (half) {
            #pragma unroll
            for (int c = 0; c < CC; c++) lds_h[c * HP + b] = acc[c];
        }
        __syncthreads();
        if (!half) {
            #pragma unroll
            for (int c = 0; c < CC; c++) lds_h[c * HP + b] += acc[c];
        }
        __syncthreads();

        // ---- bn1 stats (per c over 128 b) ----
        {
            int c = tid & 15, r = tid >> 4;
            float s = 0.f, ss = 0.f;
            #pragma unroll
            for (int i = 0; i < 8; i++) {
                float v = lds_h[c * HP + r * 8 + i];
                s += v; ss += v * v;
            }
            red_s[tid] = s; red_ss[tid] = ss;
        }
        __syncthreads();
        if (tid < CC) {
            float S = 0.f, SS = 0.f;
            #pragma unroll
            for (int r = 0; r < 16; r++) { S += red_s[r * 16 + tid]; SS += red_ss[r * 16 + tid]; }
            float mean = S * (1.0f / 128.0f);
            float var = SS * (1.0f / 128.0f) - mean * mean;
            float scale = rsqrtf(var + EPSV) * g1[n * CC + tid];
            sc[tid] = scale;
            sh[tid] = be1[n * CC + tid] - mean * scale;
        }
        __syncthreads();

        // apply bn1 + elu in place
        for (int idx = tid; idx < CC * BB; idx += 256) {
            int c = idx >> 7, b2 = idx & 127;
            float a = lds_h[c * HP + b2] * sc[c] + sh[c];
            a = (a > 0.0f) ? a : (__expf(a) - 1.0f);
            lds_h[c * HP + b2] = a;
        }
        __syncthreads();

        // ---- 16x16 matmul: thread (d = tid&15, brow = tid>>4) ----
        int d = tid & 15, brow = tid >> 4;
        float h2[8];
        #pragma unroll
        for (int j = 0; j < 8; j++) {
            float a2 = 0.f;
            #pragma unroll
            for (int c = 0; c < CC; c++)
                a2 += lds_h[c * HP + brow + 16 * j] * lds_w2[c * 16 + d];
            h2[j] = a2;
        }

        // ---- bn2 stats ----
        float s = 0.f, ss = 0.f;
        #pragma unroll
        for (int j = 0; j < 8; j++) { s += h2[j]; ss += h2[j] * h2[j]; }
        red_s[tid] = s; red_ss[tid] = ss;
        __syncthreads();
        if (tid < CC) {
            float S = 0.f, SS = 0.f;
            #pragma unroll
            for (int r = 0; r < 16; r++) { S += red_s[r * 16 + tid]; SS += red_ss[r * 16 + tid]; }
            float mean = S * (1.0f / 128.0f);
            float var = SS * (1.0f / 128.0f) - mean * mean;
            float scale = rsqrtf(var + EPSV) * g2[n * CC + tid];
            sc[tid] = scale;
            sh[tid] = be2[n * CC + tid] - mean * scale;
        }
        __syncthreads();

        // apply bn2 + elu, store activated tile as [d][b]
        #pragma unroll
        for (int j = 0; j < 8; j++) {
            float a = h2[j] * sc[d] + sh[d];
            a = (a > 0.0f) ? a : (__expf(a) - 1.0f);
            lds_h[d * HP + brow + 16 * j] = a;
        }
        __syncthreads();
    }

    // ---- Phase C: push to outgoing edge slots ----
    int st2 = rs[NN + n] - EE, en2 = rs[NN + n + 1] - EE;
    const bool last = (dsts != nullptr);
    for (int k0 = st2; k0 < en2; k0 += CH) {
        int m = min(CH, en2 - k0);
        if (tid < m) {
            lds_b[tid] = b3s[k0 + tid];
            if (last) {
                int dn = dsts[k0 + tid];
                lds_i[tid] = (dn >= OUT_LO) ? (dn - OUT_LO) * BB : -1;
            } else {
                lds_i[tid] = wout[k0 + tid];
            }
        }
        if (isfunc) {
            for (int idx = tid; idx < m * CC; idx += 256)
                lds_w[idx] = w3s[(size_t)k0 * CC + idx];           // contiguous
        }
        __syncthreads();
        for (int k = half; k < m; k += 2) {
            int o = lds_i[k];
            if (last && o < 0) continue;
            float dot = 0.f;
            if (isfunc) {
                const float* wr = &lds_w[k * CC];
                #pragma unroll
                for (int d2 = 0; d2 < CC; d2++) dot += lds_h[d2 * HP + b] * wr[d2];
            }
            float val = dot + lds_b[k] + x0r;
            if (last) atomicAdd(&outT[o + b], val);
            else      xe_out[o + b] = val;
        }
        __syncthreads();
    }
}

// out[b*N + n] = (n >= OUT_LO) ? outT[(n-OUT_LO)*B + b] : 0
__global__ void k_finalize(const float* __restrict__ outT, float* __restrict__ out) {
    int idx = blockIdx.x * 256 + threadIdx.x;
    if (idx < BB * NN) {
        int b = idx / NN;
        int n = idx - b * NN;
        out[idx] = (n >= OUT_LO) ? outT[(n - OUT_LO) * BB + b] : 0.0f;
    }
}

extern "C" void kernel_launch(void* const* d_in, const int* in_sizes, int n_in,
                              void* d_out, int out_size, void* d_ws, size_t ws_size,
                              hipStream_t stream) {
    const float* x   = (const float*)d_in[0];
    const float* w1  = (const float*)d_in[1];
    // d_in[2] = b1: cancels through batchnorm
    const float* w2  = (const float*)d_in[3];
    // d_in[4] = b2: cancels through batchnorm
    const float* w3  = (const float*)d_in[5];
    const float* b3  = (const float*)d_in[6];
    const float* g1  = (const float*)d_in[7];
    const float* be1 = (const float*)d_in[8];
    const float* g2  = (const float*)d_in[9];
    const float* be2 = (const float*)d_in[10];
    const int* ei    = (const int*)d_in[11];
    float* out = (float*)d_out;

    // workspace partition (16B-aligned chunks)
    char* ws = (char*)d_ws;
    float* xT   = (float*)ws;  ws += (size_t)NN * BB * 4;        // 1.0 MB
    float* xeA  = (float*)ws;  ws += (size_t)EE * BB * 4;        // 10.2 MB
    float* xeB  = (float*)ws;  ws += (size_t)EE * BB * 4;        // 10.2 MB
    float* w1s  = (float*)ws;  ws += (size_t)EE * CC * 4;        // 1.28 MB
    float* w3s  = (float*)ws;  ws += (size_t)EE * CC * 4;        // 1.28 MB
    float* b3s  = (float*)ws;  ws += (size_t)EE * 4;
    float* outT = (float*)ws;  ws += (size_t)OUTN * BB * 4;
    int* deg    = (int*)ws;    ws += (size_t)2 * NN * 4;
    int* rs     = (int*)ws;    ws += (size_t)(2 * NN + 1) * 4 + 12;
    int* cursor = (int*)ws;    ws += (size_t)2 * NN * 4;
    int* csr    = (int*)ws;    ws += (size_t)2 * EE * 4;
    int* pos    = (int*)ws;    ws += (size_t)EE * 4;
    int* row0s  = (int*)ws;    ws += (size_t)EE * 4;
    int* wout   = (int*)ws;    ws += (size_t)EE * 4;
    int* dsts   = (int*)ws;    ws += (size_t)EE * 4;

    hipMemsetAsync(deg, 0, 2 * NN * sizeof(int), stream);
    k_prep1<<<(NN * BB) / 256, 256, 0, stream>>>(x, xT, ei, deg, outT);
    k_scan<<<1, 256, 0, stream>>>(deg, rs, cursor);
    k_scatter2<<<(EE + 255) / 256, 256, 0, stream>>>(ei, cursor, csr, pos);
    k_presort<<<(EE * CC) / 256, 256, 0, stream>>>(ei, csr, pos, w1, w3, b3,
                                                   w1s, w3s, b3s, row0s, wout, dsts);

    k_layer<<<NN, 256, 0, stream>>>(xT,  row0s,   xT, w1s, w2, w3s, b3s, wout,
                                    g1, be1, g2, be2, rs, nullptr, xeA, outT);
    k_layer<<<NN, 256, 0, stream>>>(xeA, nullptr, xT, w1s, w2, w3s, b3s, wout,
                                    g1, be1, g2, be2, rs, nullptr, xeB, outT);
    k_layer<<<NN, 256, 0, stream>>>(xeB, nullptr, xT, w1s, w2, w3s, b3s, wout,
                                    g1, be1, g2, be2, rs, nullptr, xeA, outT);
    k_layer<<<NN, 256, 0, stream>>>(xeA, nullptr, xT, w1s, w2, w3s, b3s, wout,
                                    g1, be1, g2, be2, rs, dsts,    xeB, outT);

    k_finalize<<<(NN * BB) / 256, 256, 0, stream>>>(outT, out);
}